// Round 8
// baseline (752.603 us; speedup 1.0000x reference)
//
#include <hip/hip_runtime.h>
#include <math.h>

#define T_DIM 16384
#define A_DIM 128
#define K_DIM 128
#define N_STEPS 16
#define E_DIM 126
#define NSEQ 4

#define NPT0 512
#define TT 256
#define NTT 64
#define SS_LEN 383
#define PIDX(i) ((i) + ((i) >> 5))   // +1 pad per 32 dwords (step0 engine)

#define CHW 96                        // k_inc chunk width (columns)

// ---- workspace float offsets (~40.6 MiB total) ----
#define WS_DU    0                         // 16384 f
#define WS_EMB   16384                     // 8192 f
#define WS_NORM  24576                     // 16 f
#define WS_CM    24592                     // 65536 u64 = 131072 f (8B aligned)
#define WS_G     155664                    // 128*128*128 f
#define WS_S     (155664 + 2097152)        // 4*16384*128 f, layout [seq][t][a]

// order-preserving pack: bigger u64 == (bigger value, then smaller flat idx).
__device__ inline unsigned long long pack_vi(float v, int fi) {
    unsigned int b = __float_as_uint(v);
    b = (b & 0x80000000u) ? ~b : (b | 0x80000000u);
    return ((unsigned long long)b << 32) | (unsigned int)(~fi);
}
__device__ inline void unpack_vi(unsigned long long p, float* v, int* fi) {
    unsigned int lo = (unsigned int)(p & 0xffffffffu);
    unsigned int b = (unsigned int)(p >> 32);
    unsigned int fb = (b & 0x80000000u) ? (b & 0x7fffffffu) : ~b;
    *v = __uint_as_float(fb);
    *fi = (int)(~lo);
}
__device__ inline unsigned long long u64max(unsigned long long a, unsigned long long b) {
    return a > b ? a : b;
}

// ---------------------------------------------------------------------------
// du normalize (blocks 0..127) + colmax zero-init (blocks 128..191)
__global__ __launch_bounds__(256) void k_prep(
    const float* __restrict__ d, float* __restrict__ du,
    unsigned long long* __restrict__ cm) {
    int blk = blockIdx.x, tid = threadIdx.x;
    if (blk < 128) {
        __shared__ float s[128];
        float v = 0.0f;
        if (tid < 128) { v = d[blk * K_DIM + tid]; s[tid] = v * v; }
        __syncthreads();
        for (int off = 64; off > 0; off >>= 1) {
            if (tid < off) s[tid] += s[tid + off];
            __syncthreads();
        }
        if (tid < 128) du[blk * K_DIM + tid] = v / (sqrtf(s[0]) + 1e-8f);
    } else {
        int zb = blk - 128;                  // 0..63; 65536 u64 total
        #pragma unroll
        for (int q = 0; q < 4; q++)
            cm[zb * 1024 + q * 256 + tid] = 0ULL;
    }
}

// ---------------------------------------------------------------------------
// Gram cross-correlation: G[w][a][d] = sum_k du[a][k]*du[w][k+d], d in [0,128).
// For dt<0 use G[a][w][-dt]. (R19-proven.)
__global__ __launch_bounds__(256) void k_gram(
    const float* __restrict__ du, float* __restrict__ G) {
    int w = blockIdx.x >> 1, ah = blockIdx.x & 1;
    int tid = threadIdx.x;
    __shared__ float sw[128];
    __shared__ float sa[64][129];
    if (tid < 128) sw[tid] = du[w * K_DIM + tid];
    for (int i = tid; i < 64 * 128; i += 256)
        sa[i >> 7][i & 127] = du[(ah * 64 + (i >> 7)) * K_DIM + (i & 127)];
    __syncthreads();
    for (int e = 0; e < 32; e++) {
        int idx = e * 256 + tid;            // 8192 = 64 al x 128 d
        int dsh = idx >> 6;                 // uniform per 64-lane wave
        int al = idx & 63;
        float s = 0.0f;
        for (int k = 0; k < 128 - dsh; k++)
            s = fmaf(sa[al][k], sw[k + dsh], s);
        G[w * (A_DIM * K_DIM) + (ah * 64 + al) * K_DIM + dsh] = s;
    }
}

// ---------------------------------------------------------------------------
// step0: compute scores (R10/R11-proven fmaf order), store TRANSPOSED
// St[t][a] (per-lane 64B-contiguous float4 stores), and colmax via
// LDS u64 atomicMax -> one global atomicMax per column per block.
__global__ __launch_bounds__(256) void k_step0(
    const float* __restrict__ a, const float* __restrict__ b,
    const float* __restrict__ du, float* __restrict__ S,
    unsigned long long* __restrict__ cm) {
    __shared__ float rsh[408];       // max PIDX = PIDX(387) = 399
    __shared__ unsigned long long pcol[256];
    int blk = blockIdx.x, tid = threadIdx.x;
    int seq = blk >> 9, idx = blk & 511;
    int a_base = (idx >> 6) * 16, t0 = (idx & 63) * TT;
    const float* x = (seq < 2 ? a : b) + (seq & 1) * T_DIM;
    for (int i = tid; i < SS_LEN; i += 256) {
        int t = t0 - 64 + i;
        rsh[PIDX(i)] = (t >= 0 && t < T_DIM) ? x[t] : 0.0f;
    }
    pcol[tid] = 0ULL;
    __syncthreads();

    int tg = tid & 63;
    int ag = __builtin_amdgcn_readfirstlane(tid >> 6);
    const float* duP = du + (a_base + ag * 4) * K_DIM;
    int L0 = 4 * tg;
    float acc[4][4];
    #pragma unroll
    for (int i = 0; i < 4; i++)
        #pragma unroll
        for (int j = 0; j < 4; j++) acc[i][j] = 0.0f;
    float r[8];
    #pragma unroll
    for (int m = 0; m < 8; m++) r[m] = rsh[PIDX(L0 + m)];
    #pragma unroll 4
    for (int k = 0; k < K_DIM; k += 4) {
        float dA[4][4];
        #pragma unroll
        for (int i = 0; i < 4; i++)
            *(float4*)dA[i] = *(const float4*)(duP + i * K_DIM + k);
        #pragma unroll
        for (int dk = 0; dk < 4; dk++) {
            #pragma unroll
            for (int i = 0; i < 4; i++) {
                float s = dA[i][dk];
                #pragma unroll
                for (int j = 0; j < 4; j++)
                    acc[i][j] = fmaf(s, r[j + dk], acc[i][j]);
            }
        }
        r[0] = r[4]; r[1] = r[5]; r[2] = r[6]; r[3] = r[7];
        #pragma unroll
        for (int m = 0; m < 4; m++) r[4 + m] = rsh[PIDX(L0 + k + 8 + m)];
    }

    float* Sp = S + (size_t)seq * (A_DIM * T_DIM);
    #pragma unroll
    for (int jj = 0; jj < 4; jj++) {      // St[t][a]: 16B store, lane-own 64B line
        float4 vv;
        vv.x = acc[0][jj]; vv.y = acc[1][jj]; vv.z = acc[2][jj]; vv.w = acc[3][jj];
        *(float4*)(Sp + (size_t)(t0 + 4 * tg + jj) * 128 + a_base + ag * 4) = vv;
    }
    #pragma unroll
    for (int jj = 0; jj < 4; jj++) {      // per-column partial max (a ascending)
        float bv = acc[0][jj]; int bi = 0;
        #pragma unroll
        for (int i = 1; i < 4; i++)
            if (acc[i][jj] > bv) { bv = acc[i][jj]; bi = i; }
        unsigned long long pk =
            pack_vi(bv, (a_base + ag * 4 + bi) * T_DIM + t0 + 4 * tg + jj);
        atomicMax(&pcol[4 * tg + jj], pk);
    }
    __syncthreads();
    atomicMax(&cm[(size_t)seq * T_DIM + t0 + tid], pcol[tid]);
}

// ---------------------------------------------------------------------------
// Incremental MP, one block/seq, 1024 threads. Per step: winner from 64-entry
// LDS tile table; S window (<=255 cols x 128 atoms, contiguous in St[t][a])
// processed in 3 LDS-staged chunks: coalesced stage-in, batched independent
// G loads, RMW entirely in LDS, shfl column-reduce -> colmax, coalesced
// write-back. Tile maxes recomputed from colmax for the <=2 affected tiles.
__global__ __launch_bounds__(1024) void k_inc(
    const float* __restrict__ a, const float* __restrict__ b,
    const float* __restrict__ du, const float* __restrict__ G,
    float* __restrict__ S, unsigned long long* __restrict__ colmax,
    const float* __restrict__ ae, float* __restrict__ emb,
    float* __restrict__ normsG) {
    __shared__ __align__(16) unsigned long long SMI[6432];
    float* stage = (float*)SMI;                       // 12288 f (48 KB)
    unsigned long long* pc  = SMI + 6144;             // 192
    unsigned long long* tm  = SMI + 6336;             // 64
    unsigned long long* red = SMI + 6400;             // 16
    float* fred             = (float*)(SMI + 6416);   // 16 f
    unsigned long long* wshp = SMI + 6424;            // 1
    float* sn2p             = (float*)(SMI + 6425);   // 1

    int seq = blockIdx.x, tid = threadIdx.x;
    const float* x = (seq < 2 ? a : b) + (seq & 1) * T_DIM;
    float* Ssq = S + (size_t)seq * (A_DIM * T_DIM);
    unsigned long long* cm = colmax + (size_t)seq * T_DIM;

    {   // tile-max table init from colmax
        int ttile = tid >> 4, r = tid & 15;
        unsigned long long m = 0ULL;
        const unsigned long long* basep = cm + ttile * 256 + r * 16;
        #pragma unroll
        for (int q = 0; q < 16; q++) m = u64max(m, basep[q]);
        #pragma unroll
        for (int off = 8; off > 0; off >>= 1)
            m = u64max(m, __shfl_down(m, off));
        if (r == 0) tm[ttile] = m;
    }
    {   // ||x||^2
        float s = 0.0f;
        for (int t = tid; t < T_DIM; t += 1024) {
            float v = x[t]; s = fmaf(v, v, s);
        }
        #pragma unroll
        for (int off = 32; off > 0; off >>= 1) s += __shfl_down(s, off);
        if ((tid & 63) == 0) fred[tid >> 6] = s;
    }
    __syncthreads();
    if (tid == 0) {
        float t = 0.0f;
        for (int q = 0; q < 16; q++) t += fred[q];
        sn2p[0] = t;
    }
    __syncthreads();

    for (int step = 0; step < N_STEPS; step++) {
        if (tid < 64) {                     // winner
            unsigned long long m = tm[tid];
            #pragma unroll
            for (int off = 32; off > 0; off >>= 1)
                m = u64max(m, __shfl_down(m, off));
            if (tid == 0) wshp[0] = m;
        }
        __syncthreads();
        float v; int fi;
        unpack_vi(wshp[0], &v, &fi);
        int w = fi >> 14, wt = fi & (T_DIM - 1);
        {                                   // embedding row
            float* e = emb + (seq * N_STEPS + step) * 128;
            int pos_idx = v > 0.0f ? wt : 0;
            int aidx = v > 0.0f ? w : 0;
            if (tid == 0) {
                e[0] = ((float)pos_idx / (float)(T_DIM - 1)) * 20.0f;
                e[1] = v;
            }
            if (tid >= 2 && tid < 128) e[tid] = ae[aidx * E_DIM + tid - 2];
        }
        if (tid < 128) {                    // Q_clip partials
            int t_res = wt + tid - 64;
            float q = 0.0f;
            if (t_res >= 0 && t_res < T_DIM) {
                float dv = du[w * K_DIM + tid];
                q = dv * dv;
            }
            #pragma unroll
            for (int off = 32; off > 0; off >>= 1) q += __shfl_down(q, off);
            if ((tid & 63) == 0) fred[8 + (tid >> 6)] = q;
        }
        __syncthreads();
        if (tid == 0) {                     // ||res'||^2 = ||res||^2 - v^2(2-Q)
            float Q = fred[8] + fred[9];
            sn2p[0] = sn2p[0] - v * v * (2.0f - Q);
        }

        if (step < N_STEPS - 1) {
            int lo = wt - 127; if (lo < 0) lo = 0;
            int hi = wt + 127; if (hi > T_DIM - 1) hi = T_DIM - 1;
            bool edge = (wt < 64) || (wt > T_DIM - 65);
            int j = tid >> 7, A_ = tid & 127;

            int nch = (hi - lo + CHW) / CHW;
            for (int ch = 0; ch < nch; ch++) {
                int clo = lo + ch * CHW;
                int cw = hi - clo + 1; if (cw > CHW) cw = CHW;
                int W4 = cw * 32;                      // float4 count
                float4* g4 = (float4*)(Ssq + (size_t)clo * 128);
                for (int i4 = tid; i4 < W4; i4 += 1024)
                    ((float4*)stage)[i4] = g4[i4];
                __syncthreads();

                int np = (cw + 7) >> 3;                // <= 12
                float cv[12];
                #pragma unroll
                for (int p = 0; p < 12; p++) {         // batched G loads
                    if (p >= np) break;
                    int cc_ = p * 8 + j;
                    bool act = (cc_ < cw);
                    float ccv = 0.0f;
                    if (act && !edge) {
                        int dt = clo + cc_ - wt;
                        int neg = dt < 0;
                        int r0 = neg ? A_ : w;
                        int r1 = neg ? w : A_;
                        int dd = neg ? -dt : dt;
                        ccv = G[((size_t)r0 * 128 + r1) * 128 + dd];
                    }
                    cv[p] = ccv;
                }
                #pragma unroll
                for (int p = 0; p < 12; p++) {
                    if (p >= np) break;
                    int cc_ = p * 8 + j;
                    unsigned long long pk = 0ULL;
                    if (cc_ < cw) {
                        int t = clo + cc_;
                        float c = cv[p];
                        if (edge) {                     // exact clipped corr
                            int dt = t - wt;
                            int jlo = dt > 0 ? dt : 0;
                            { int bnd = 64 - wt; if (bnd > jlo) jlo = bnd; }
                            int jhi = dt + 127; if (jhi > 127) jhi = 127;
                            { int bnd = T_DIM + 63 - wt; if (bnd < jhi) jhi = bnd; }
                            float ds = 0.0f;
                            for (int jj = jlo; jj <= jhi; jj++)
                                ds = fmaf(du[w * K_DIM + jj],
                                          du[A_ * K_DIM + jj - dt], ds);
                            c = ds;
                        }
                        int li = cc_ * 128 + A_;
                        float ov = stage[li];
                        float nv = __fsub_rn(ov, __fmul_rn(v, c));
                        stage[li] = nv;
                        pk = pack_vi(nv, A_ * T_DIM + t);
                    }
                    #pragma unroll
                    for (int off = 32; off > 0; off >>= 1)
                        pk = u64max(pk, __shfl_down(pk, off));
                    if ((tid & 63) == 0)
                        pc[cc_ * 2 + ((tid >> 6) & 1)] = pk;
                }
                __syncthreads();
                if (tid < CHW && tid < cw)             // merge + colmax write
                    cm[clo + tid] = u64max(pc[tid * 2], pc[tid * 2 + 1]);
                for (int i4 = tid; i4 < W4; i4 += 1024)   // write-back
                    g4[i4] = ((float4*)stage)[i4];
                __syncthreads();
            }

            // recompute tile maxes for the affected tiles from colmax
            int Tlo = lo >> 8, Thi = hi >> 8;
            int ntile = Thi - Tlo + 1;                 // 1 or 2
            if (tid < ntile * 256) {
                int Tt = Tlo + (tid >> 8);
                unsigned long long mv = cm[Tt * 256 + (tid & 255)];
                #pragma unroll
                for (int off = 32; off > 0; off >>= 1)
                    mv = u64max(mv, __shfl_down(mv, off));
                if ((tid & 63) == 0) red[tid >> 6] = mv;
            }
            __syncthreads();
            if (tid < ntile) {
                unsigned long long m =
                    u64max(u64max(red[tid * 4 + 0], red[tid * 4 + 1]),
                           u64max(red[tid * 4 + 2], red[tid * 4 + 3]));
                tm[Tlo + tid] = m;
            }
            __syncthreads();
        }
    }
    if (tid == 0) normsG[seq] = sqrtf(sn2p[0]);
}

// ---------------------------------------------------------------------------
__global__ __launch_bounds__(256) void k_tail(
    const float* __restrict__ emb, const float* __restrict__ normsG,
    const float* __restrict__ proj, float* __restrict__ out) {
    __shared__ float keys[64];
    __shared__ int order[64];
    __shared__ float sh[256];
    __shared__ float norms[4];
    int tid = threadIdx.x;
    if (tid < NSEQ) norms[tid] = normsG[tid];
    if (tid < 64) {
        int seq = tid >> 4, st = tid & 15;
        const float* e = emb + (seq * N_STEPS + st) * 128;
        float kk = 0.0f;
        for (int dd = 0; dd < 128; dd++) kk = fmaf(e[dd], proj[dd], kk);
        keys[tid] = kk;
    }
    __syncthreads();
    if (tid < NSEQ) {
        int ord[N_STEPS];
        for (int i = 0; i < N_STEPS; i++) ord[i] = i;
        for (int i = 1; i < N_STEPS; i++) {     // stable ascending
            int oi = ord[i];
            float kv = keys[tid * N_STEPS + oi];
            int j = i - 1;
            while (j >= 0 && keys[tid * N_STEPS + ord[j]] > kv) {
                ord[j + 1] = ord[j]; j--;
            }
            ord[j + 1] = oi;
        }
        for (int i = 0; i < N_STEPS; i++) order[tid * N_STEPS + i] = ord[i];
    }
    __syncthreads();
    float s = 0.0f;
    #pragma unroll
    for (int t = 0; t < 16; t++) {
        int idx = tid + t * 256;
        int bq = idx >> 11;
        int st = (idx >> 7) & 15;
        int dd = idx & 127;
        float va = emb[((bq    ) * N_STEPS + order[bq * N_STEPS + st]) * 128 + dd];
        float vb = emb[((2 + bq) * N_STEPS + order[(2 + bq) * N_STEPS + st]) * 128 + dd];
        float df = va - vb;
        s = fmaf(df, df, s);
    }
    sh[tid] = s;
    __syncthreads();
    for (int off = 128; off > 0; off >>= 1) {
        if (tid < off) sh[tid] += sh[tid + off];
        __syncthreads();
    }
    if (tid == 0) {
        float mse = sh[0] / 4096.0f;
        float mad = 0.5f * (fabsf(norms[0] - norms[2]) + fabsf(norms[1] - norms[3]));
        out[0] = mse + mad;
    }
}

// ---------------------------------------------------------------------------
extern "C" void kernel_launch(void* const* d_in, const int* in_sizes, int n_in,
                              void* d_out, int out_size, void* d_ws, size_t ws_size,
                              hipStream_t stream) {
    const float* a    = (const float*)d_in[0];
    const float* b    = (const float*)d_in[1];
    const float* d    = (const float*)d_in[2];
    const float* ae   = (const float*)d_in[3];
    const float* proj = (const float*)d_in[4];
    float* out = (float*)d_out;

    float* ws     = (float*)d_ws;            // needs ~40.6 MiB
    float* du     = ws + WS_DU;
    float* emb    = ws + WS_EMB;
    float* normsG = ws + WS_NORM;
    unsigned long long* cm = (unsigned long long*)(ws + WS_CM);
    float* G      = ws + WS_G;
    float* S      = ws + WS_S;

    k_prep <<<192,  256, 0, stream>>>(d, du, cm);
    k_gram <<<256,  256, 0, stream>>>(du, G);
    k_step0<<<2048, 256, 0, stream>>>(a, b, du, S, cm);
    k_inc  <<<4,   1024, 0, stream>>>(a, b, du, G, S, cm, ae, emb, normsG);
    k_tail <<<1,    256, 0, stream>>>(emb, normsG, proj, out);
}